// Round 13
// baseline (100.528 us; speedup 1.0000x reference)
//
#include <hip/hip_runtime.h>
#include <hip/hip_bf16.h>

// EmbeddingPredictor: B=16 T=2048 V=32000 E=512 H=4 C=3, f32 in/out.
// R13: single-pass table. out_t = (1/12)*sum_c s_c*XW[tok_{t-2+c}] + bias,
//      s_c = EP[tok][c];  XW = table @ W^T (bf16 MFMA);  EP = table @ P (f32, inline).
//  K0 prep:   Pt[3][512] f32; Wb bf16
//  K1 xw:     block = 32 vocab rows x full N=512 (8 waves x 64 cols, acc[2][4]).
//             A staged upfront (f32 global -> f32 regs -> EP f32 dots + shfl ->
//             bf16 swizzled LDS, 4 rounds, wave-per-row), then BARRIER-FREE K-loop
//             (A from LDS, B direct from L2-resident Wb). Table read exactly once.
//  K2 gather: wave-per-token streaming: 3 EP scalars + 3 XW bf16 rows -> combine ->
//             bias + LayerNorm + swish -> f32 out.
// ws: Pt @0 (8KB), Wb @16K (512KB), EP @1M (512KB), XW @2M (32.8MB).

#define Bq 16
#define Tq 2048
#define Eq 512
#define Cq 3
#define Hq 4
#define Vq 32000
#define Mq (Bq * Tq)
#define LN_EPS 1e-5f

typedef __attribute__((ext_vector_type(8))) short bf16x8;
typedef __attribute__((ext_vector_type(4))) float f32x4;

__device__ __forceinline__ unsigned short f2bf(float f) {
    unsigned int u = __float_as_uint(f);
    u += 0x7fffu + ((u >> 16) & 1u);   // RNE
    return (unsigned short)(u >> 16);
}
__device__ __forceinline__ float bf2f(unsigned short h) {
    return __uint_as_float(((unsigned int)h) << 16);
}
__device__ __forceinline__ unsigned int cvt_pk_bf16(float lo, float hi) {
    unsigned int r;
    asm("v_cvt_pk_bf16_f32 %0, %1, %2" : "=v"(r) : "v"(lo), "v"(hi));
    return r;   // low16 = bf16(lo), high16 = bf16(hi), RNE
}

// ---------------- K0: prep ----------------
__global__ void prep_kernel(const float* __restrict__ pos,
                            const float* __restrict__ ffn_w,
                            float* __restrict__ Pt,            // [C][512] f32
                            unsigned short* __restrict__ Wb) { // [512][512] bf16 [n][k]
    int i = blockIdx.x * blockDim.x + threadIdx.x;   // 16384 threads
    if (i < Cq * Eq) {
        int c = i / Eq, e = i % Eq;
        float s = 0.f;
#pragma unroll
        for (int h = 0; h < Hq; ++h) s += pos[(h * Eq + e) * Cq + c];
        Pt[i] = s;
    }
    for (int j = i; j < Eq * Eq; j += 16384) Wb[j] = f2bf(ffn_w[j]);
}

// ---------------- K1: XW = table @ W^T  (+ inline f32 EP) ----------------
// grid = V/32 = 1000 blocks, 512 threads (8 waves).
// Staging round r (r=0..3): wave w owns row 8r+w; lane l covers the 16B bf16 chunk at
// swizzled byte (l*16)^((row&7)<<4)  (<=> 8 f32 elements at k0 = that/2).
// EP: s[c] = full-wave f32 dot(x_row, Pt[c]) via shfl; lane<3 writes EP.
// K-loop: NO barriers; af from swizzled LDS; bfv direct from L2 Wb.
__global__ __launch_bounds__(512, 4) void xw_kernel(const float* __restrict__ tbl,
                                                    const unsigned short* __restrict__ Wb,
                                                    const float* __restrict__ Pt,
                                                    unsigned short* __restrict__ XW,
                                                    float* __restrict__ EP) {
    __shared__ __align__(16) char Albs[32 * 1024];   // 32 rows x 1KB (bf16, swizzled)

    const int tid = threadIdx.x;
    const int wave = tid >> 6;
    const int lane = tid & 63;
    const int lr = lane & 15;
    const int lg = lane >> 4;
    const int m0 = (int)blockIdx.x << 5;

    // ---- stage A + inline EP (4 rounds, wave-per-row) ----
#pragma unroll
    for (int r = 0; r < 4; ++r) {
        const int row = (r << 3) + wave;                       // 0..31
        const int swz = (row & 7) << 4;
        const int kb16 = (lane << 4) ^ swz;                    // byte offset in bf16 row image
        const int k0 = kb16 >> 1;                              // element offset (8 f32)
        const float* src = tbl + (long)(m0 + row) * Eq + k0;
        const float4 v0 = reinterpret_cast<const float4*>(src)[0];
        const float4 v1 = reinterpret_cast<const float4*>(src)[1];

        // EP partial dots (f32)
        float s0 = 0.f, s1 = 0.f, s2 = 0.f;
        {
            const float4* p0 = reinterpret_cast<const float4*>(Pt + 0 * Eq + k0);
            const float4* p1 = reinterpret_cast<const float4*>(Pt + 1 * Eq + k0);
            const float4* p2 = reinterpret_cast<const float4*>(Pt + 2 * Eq + k0);
            const float4 a0 = p0[0], a1 = p0[1];
            const float4 b0 = p1[0], b1 = p1[1];
            const float4 c0 = p2[0], c1 = p2[1];
            s0 = v0.x * a0.x + v0.y * a0.y + v0.z * a0.z + v0.w * a0.w
               + v1.x * a1.x + v1.y * a1.y + v1.z * a1.z + v1.w * a1.w;
            s1 = v0.x * b0.x + v0.y * b0.y + v0.z * b0.z + v0.w * b0.w
               + v1.x * b1.x + v1.y * b1.y + v1.z * b1.z + v1.w * b1.w;
            s2 = v0.x * c0.x + v0.y * c0.y + v0.z * c0.z + v0.w * c0.w
               + v1.x * c1.x + v1.y * c1.y + v1.z * c1.z + v1.w * c1.w;
        }
#pragma unroll
        for (int m = 1; m < 64; m <<= 1) {
            s0 += __shfl_xor(s0, m, 64);
            s1 += __shfl_xor(s1, m, 64);
            s2 += __shfl_xor(s2, m, 64);
        }
        if (lane < 3) {
            const float sv = (lane == 0) ? s0 : (lane == 1) ? s1 : s2;
            EP[(long)(m0 + row) * 4 + lane] = sv;
        }

        // pack to bf16, store to LDS at phys = row*1024 + lane*16 (holds logical kb16)
        uint4 o;
        o.x = cvt_pk_bf16(v0.x, v0.y);
        o.y = cvt_pk_bf16(v0.z, v0.w);
        o.z = cvt_pk_bf16(v1.x, v1.y);
        o.w = cvt_pk_bf16(v1.z, v1.w);
        *reinterpret_cast<uint4*>(Albs + row * 1024 + (lane << 4)) = o;
    }
    __syncthreads();

    // ---- K-loop: no barriers. Wave w: cols [64w, 64w+64), all 32 rows ----
    const int n0 = wave << 6;
    const short* Bp = reinterpret_cast<const short*>(Wb) + (long)n0 * Eq;

    f32x4 acc[2][4];
#pragma unroll
    for (int i = 0; i < 2; ++i)
#pragma unroll
        for (int j = 0; j < 4; ++j) acc[i][j] = (f32x4){0.f, 0.f, 0.f, 0.f};

#pragma unroll
    for (int kb = 0; kb < 8; ++kb) {
#pragma unroll
        for (int ks = 0; ks < 2; ++ks) {
            bf16x8 af[2], bfv[4];
#pragma unroll
            for (int nf = 0; nf < 4; ++nf)
                bfv[nf] = *reinterpret_cast<const bf16x8*>(Bp + (nf * 16 + lr) * Eq + kb * 64 + ks * 32 + lg * 8);
#pragma unroll
            for (int mf = 0; mf < 2; ++mf) {
                const int r = mf * 16 + lr;
                af[mf] = *reinterpret_cast<const bf16x8*>(
                    Albs + r * 1024 + ((kb * 128 + ks * 64 + lg * 16) ^ ((r & 7) << 4)));
            }
#pragma unroll
            for (int mf = 0; mf < 2; ++mf)
#pragma unroll
                for (int nf = 0; nf < 4; ++nf)
                    acc[mf][nf] = __builtin_amdgcn_mfma_f32_16x16x32_bf16(af[mf], bfv[nf], acc[mf][nf], 0, 0, 0);
        }
    }

    // ---- epilogue: store XW bf16 ----
#pragma unroll
    for (int mf = 0; mf < 2; ++mf)
#pragma unroll
        for (int i = 0; i < 4; ++i) {
            const int row = m0 + mf * 16 + (lg << 2) + i;
#pragma unroll
            for (int nf = 0; nf < 4; ++nf) {
                const int col = n0 + nf * 16 + lr;
                XW[(long)row * Eq + col] = f2bf(acc[mf][nf][i]);
            }
        }
}

// ---------------- K2: gather + combine + bias + LayerNorm + swish ----------------
// grid = M/8 = 4096 blocks, 512 threads (8 waves), wave per token.
__global__ __launch_bounds__(512, 4) void gather_kernel(const int* __restrict__ tokens,
                                                        const unsigned short* __restrict__ XW,
                                                        const float* __restrict__ EP,
                                                        const float* __restrict__ bias,
                                                        const float* __restrict__ ln_g,
                                                        const float* __restrict__ ln_b,
                                                        float* __restrict__ out) {
    const int wave = threadIdx.x >> 6;
    const int lane = threadIdx.x & 63;
    const int tt = blockIdx.x * 8 + wave;   // 0..M-1
    const int t = tt & (Tq - 1);
    const int e0 = lane * 8;

    float v[8];
#pragma unroll
    for (int j = 0; j < 8; ++j) v[j] = 0.f;

#pragma unroll
    for (int c = 0; c < Cq; ++c) {
        if (t + c >= 2) {                         // token t-2+c exists
            const int tok = tokens[tt + c - 2];
            const float s = EP[(long)tok * 4 + c];
            const bf16x8 xv = *reinterpret_cast<const bf16x8*>(XW + (long)tok * Eq + e0);
#pragma unroll
            for (int j = 0; j < 8; ++j)
                v[j] += s * bf2f((unsigned short)xv[j]);
        }
    }

    const float inv = 1.f / (Hq * Cq);
    const float4* bp = reinterpret_cast<const float4*>(bias + e0);
    const float4 b0 = bp[0], b1 = bp[1];
    float o[8];
    o[0] = v[0] * inv + b0.x; o[1] = v[1] * inv + b0.y;
    o[2] = v[2] * inv + b0.z; o[3] = v[3] * inv + b0.w;
    o[4] = v[4] * inv + b1.x; o[5] = v[5] * inv + b1.y;
    o[6] = v[6] * inv + b1.z; o[7] = v[7] * inv + b1.w;

    float sm = 0.f, sq = 0.f;
#pragma unroll
    for (int j = 0; j < 8; ++j) { sm += o[j]; sq += o[j] * o[j]; }
#pragma unroll
    for (int m = 1; m < 64; m <<= 1) {
        sm += __shfl_xor(sm, m, 64);
        sq += __shfl_xor(sq, m, 64);
    }
    const float mu = sm * (1.f / Eq);
    const float var = sq * (1.f / Eq) - mu * mu;
    const float rs = rsqrtf(var + LN_EPS);

    const float4* gp = reinterpret_cast<const float4*>(ln_g + e0);
    const float4* lp = reinterpret_cast<const float4*>(ln_b + e0);
    const float4 g0 = gp[0], g1 = gp[1];
    const float4 l0 = lp[0], l1 = lp[1];
    float gg[8] = {g0.x, g0.y, g0.z, g0.w, g1.x, g1.y, g1.z, g1.w};
    float ll[8] = {l0.x, l0.y, l0.z, l0.w, l1.x, l1.y, l1.z, l1.w};

    float4 r0, r1;
    float* rr0 = reinterpret_cast<float*>(&r0);
    float* rr1 = reinterpret_cast<float*>(&r1);
#pragma unroll
    for (int j = 0; j < 8; ++j) {
        float y = (o[j] - mu) * rs * gg[j] + ll[j];
        y = y / (1.f + __expf(-y));   // swish
        if (j < 4) rr0[j] = y; else rr1[j - 4] = y;
    }
    float4* op = reinterpret_cast<float4*>(out + (long)tt * Eq + e0);
    op[0] = r0;
    op[1] = r1;
}

extern "C" void kernel_launch(void* const* d_in, const int* in_sizes, int n_in,
                              void* d_out, int out_size, void* d_ws, size_t ws_size,
                              hipStream_t stream) {
    const int* tokens = (const int*)d_in[0];
    const float* tbl = (const float*)d_in[1];
    const float* pos = (const float*)d_in[2];
    const float* ffn_w = (const float*)d_in[3];
    const float* ffn_b = (const float*)d_in[4];
    const float* ln_g = (const float*)d_in[5];
    const float* ln_b = (const float*)d_in[6];
    float* out = (float*)d_out;

    char* ws = (char*)d_ws;
    float* Pt = (float*)ws;                                   // 8 KB
    unsigned short* Wb = (unsigned short*)(ws + 16384);       // 512 KB
    float* EP = (float*)(ws + (1 << 20));                     // 512 KB
    unsigned short* XW = (unsigned short*)(ws + (2 << 20));   // 32.8 MB

    hipLaunchKernelGGL(prep_kernel, dim3(64), dim3(256), 0, stream, pos, ffn_w, Pt, Wb);
    hipLaunchKernelGGL(xw_kernel, dim3(Vq / 32), dim3(512), 0, stream, tbl, Wb, Pt, XW, EP);
    hipLaunchKernelGGL(gather_kernel, dim3(Mq / 8), dim3(512), 0, stream,
                       tokens, XW, EP, ffn_b, ln_g, ln_b, out);
}